// Round 1
// baseline (110.368 us; speedup 1.0000x reference)
//
#include <hip/hip_runtime.h>

#define B 16
#define S 4096
#define V 128
#define TRUNC 11
#define T_LIM (S - TRUNC)   // 4085

#define NC 512              // chunks over t
#define CT (S / NC)         // 8

// log2(0.99), 1/0.99
#define LOG2_GAMMA (-0.014499569695115089f)
#define INV_GAMMA 1.0101010101010102f

__device__ __forceinline__ float log_sigmoid(float x) {
    float e = __expf(-fabsf(x));
    return fminf(x, 0.0f) - __logf(1.0f + e);
}

// Thread (c, b, v4): per v in the float4 group computes, over t in its chunk:
//   A = sum w[t]*ls[t]*local_lp_prefix[t]   (lp prefix restricted to t < T_LIM)
//   W = sum w[t]*ls[t]
//   L = sum_{t<T_LIM} lp[t]
// Packed store: pAWL[bv*NC + c] = {A, W, L, 0} — one dwordx4 per bv instead of
// 3 scalar scattered stores. Combine reads each row contiguously.
__global__ __launch_bounds__(256, 4) void partials_kernel(
    const float4* __restrict__ lp,   // [S][B][V/4]
    const float4* __restrict__ lg,   // [B][S][V/4]
    float4* __restrict__ pAWL)       // [B*V][NC]
{
    int tid = blockIdx.x * blockDim.x + threadIdx.x;
    int v4 = tid & (V / 4 - 1);          // 0..31
    int b  = (tid >> 5) & (B - 1);       // 0..15
    int c  = tid >> 9;                   // 0..NC-1 (wave-uniform)
    int t0 = c * CT;

    const float4* lp_p = lp + (size_t)t0 * (B * V / 4) + b * (V / 4) + v4;
    const float4* lg_p = lg + (size_t)b * (S * V / 4) + (size_t)t0 * (V / 4) + v4;

    // Prefetch everything: 16 independent dwordx4 loads in flight before any use.
    float4 Lv[CT], Gv[CT];
    #pragma unroll
    for (int i = 0; i < CT; ++i) Lv[i] = lp_p[(size_t)i * (B * V / 4)];
    #pragma unroll
    for (int i = 0; i < CT; ++i) Gv[i] = lg_p[(size_t)i * (V / 4)];

    float w = exp2f(LOG2_GAMMA * (float)(S - t0));

    float ax = 0.f, ay = 0.f, az = 0.f, aw = 0.f;
    float Ax = 0.f, Ay = 0.f, Az = 0.f, Aw = 0.f;
    float Wx = 0.f, Wy = 0.f, Wz = 0.f, Ww = 0.f;

    #pragma unroll
    for (int i = 0; i < CT; ++i) {
        int t = t0 + i;
        if (t < T_LIM) {                 // wave-uniform (c uniform per wave)
            ax += Lv[i].x; ay += Lv[i].y; az += Lv[i].z; aw += Lv[i].w;
        }
        float sx = w * log_sigmoid(Gv[i].x);
        float sy = w * log_sigmoid(Gv[i].y);
        float sz = w * log_sigmoid(Gv[i].z);
        float sw = w * log_sigmoid(Gv[i].w);
        Ax = fmaf(sx, ax, Ax);
        Ay = fmaf(sy, ay, Ay);
        Az = fmaf(sz, az, Az);
        Aw = fmaf(sw, aw, Aw);
        Wx += sx; Wy += sy; Wz += sz; Ww += sw;
        w *= INV_GAMMA;
    }

    int bv0 = b * V + v4 * 4;
    float4 o0 = {Ax, Wx, ax, 0.f};
    float4 o1 = {Ay, Wy, ay, 0.f};
    float4 o2 = {Az, Wz, az, 0.f};
    float4 o3 = {Aw, Ww, aw, 0.f};
    pAWL[(size_t)(bv0 + 0) * NC + c] = o0;
    pAWL[(size_t)(bv0 + 1) * NC + c] = o1;
    pAWL[(size_t)(bv0 + 2) * NC + c] = o2;
    pAWL[(size_t)(bv0 + 3) * NC + c] = o3;
}

// One wave per (b,v). Lane l owns chunks 8l..8l+7 (8 contiguous float4).
// Exclusive scan of L across chunks -> prefix; E = sum(A + prefix*W).
__global__ __launch_bounds__(256) void combine_kernel(
    const float4* __restrict__ pAWL,  // [B*V][NC] of {A,W,L,0}
    float* __restrict__ out)
{
    int gtid = blockIdx.x * blockDim.x + threadIdx.x;
    int bv   = gtid >> 6;
    int lane = threadIdx.x & 63;
    if (bv >= B * V) return;

    const float4* row = pAWL + (size_t)bv * NC + lane * (NC / 64);  // 8 per lane
    float4 f[NC / 64];
    #pragma unroll
    for (int k = 0; k < NC / 64; ++k) f[k] = row[k];

    // intra-lane exclusive prefixes of L over the 8 chunks
    float pk[NC / 64];
    float s = 0.f;
    #pragma unroll
    for (int k = 0; k < NC / 64; ++k) { pk[k] = s; s += f[k].z; }

    // inclusive wave scan of lane totals, then make exclusive
    float scan = s;
    #pragma unroll
    for (int off = 1; off < 64; off <<= 1) {
        float n = __shfl_up(scan, off, 64);
        if (lane >= off) scan += n;
    }
    float base = scan - s;               // exclusive prefix across lanes

    float E = 0.f;
    #pragma unroll
    for (int k = 0; k < NC / 64; ++k)
        E = fmaf(base + pk[k], f[k].y, E + f[k].x);

    // wave reduction
    #pragma unroll
    for (int off = 32; off > 0; off >>= 1)
        E += __shfl_down(E, off, 64);

    if (lane == 0) out[bv] = E;
}

// Fallback if workspace is too small: direct single-pass, one thread per (b,v4).
__global__ void fallback_kernel(
    const float4* __restrict__ lp,
    const float4* __restrict__ lg,
    float4* __restrict__ out)            // [B*V/4]
{
    int tid = blockIdx.x * blockDim.x + threadIdx.x;
    if (tid >= B * V / 4) return;
    int v4 = tid & (V / 4 - 1);
    int b  = tid >> 5;

    const float4* lp_p = lp + (size_t)b * (V / 4) + v4;
    const float4* lg_p = lg + (size_t)b * (S * V / 4) + v4;

    float w = exp2f(LOG2_GAMMA * (float)S);
    float ax = 0.f, ay = 0.f, az = 0.f, aw = 0.f;
    float Ax = 0.f, Ay = 0.f, Az = 0.f, Aw = 0.f;

    for (int t = 0; t < S; ++t) {
        float4 l = lp_p[(size_t)t * (B * V / 4)];
        float4 x = lg_p[(size_t)t * (V / 4)];
        if (t < T_LIM) { ax += l.x; ay += l.y; az += l.z; aw += l.w; }
        Ax = fmaf(w * log_sigmoid(x.x), ax, Ax);
        Ay = fmaf(w * log_sigmoid(x.y), ay, Ay);
        Az = fmaf(w * log_sigmoid(x.z), az, Az);
        Aw = fmaf(w * log_sigmoid(x.w), aw, Aw);
        w *= INV_GAMMA;
    }
    float4 o = {Ax, Ay, Az, Aw};
    out[tid] = o;
}

extern "C" void kernel_launch(void* const* d_in, const int* in_sizes, int n_in,
                              void* d_out, int out_size, void* d_ws, size_t ws_size,
                              hipStream_t stream)
{
    const float4* lp = (const float4*)d_in[0];   // log_probs [S,B,V] f32
    const float4* lg = (const float4*)d_in[1];   // logits    [B,S,V] f32
    float* out = (float*)d_out;                   // [B,V] f32

    size_t bytes = (size_t)NC * (B * V) * sizeof(float4);   // 16 MiB
    if (bytes > ws_size) {
        fallback_kernel<<<(B * V / 4 + 255) / 256, 256, 0, stream>>>(
            lp, lg, (float4*)out);
        return;
    }

    float4* pAWL = (float4*)d_ws;

    int threads1 = NC * (B * V / 4);              // 262144 -> 1024 blocks (4/CU)
    partials_kernel<<<(threads1 + 255) / 256, 256, 0, stream>>>(lp, lg, pAWL);

    int threads2 = B * V * 64;                    // 131072 -> 512 blocks
    combine_kernel<<<(threads2 + 255) / 256, 256, 0, stream>>>(pAWL, out);
}